// Round 6
// baseline (638.734 us; speedup 1.0000x reference)
//
#include <hip/hip_runtime.h>
#include <math.h>

#define NODES  50000
#define EDGES  800000
#define GRAPHS 256
#define FEAT   128
#define STATE  64
#define M_OUT  32
#define ROUNDS 4
#define NTILES ((NODES + 15) / 16)

typedef unsigned short bfraw;

__device__ __forceinline__ float bf2f(bfraw u) {
    union { unsigned int i; float f; } v; v.i = ((unsigned int)u) << 16; return v.f;
}
__device__ __forceinline__ bfraw f2bf(float f) {
    union { float f; unsigned int i; } v; v.f = f;
    unsigned int r = v.i + 0x7FFF + ((v.i >> 16) & 1); // round-nearest-even
    return (bfraw)(r >> 16);
}

// ---------------------------------------------------------------------------
// 8-deep gather over bf16 message rows: sum of msg[csr[beg..end)] 4-feat
// slices at offset jg. Tail indices clamped to end-1, masked by 0-multiplier.
// ---------------------------------------------------------------------------
__device__ __forceinline__ float4 gather_sum8(const int* __restrict__ csr,
                                              const bfraw* __restrict__ msg,
                                              int beg, int end, int jg)
{
    float4 acc = make_float4(0.f, 0.f, 0.f, 0.f);
    for (int i = beg; i < end; i += 8) {
        int last = end - 1;
        int i1 = i + 1 < last ? i + 1 : last;
        int i2 = i + 2 < last ? i + 2 : last;
        int i3 = i + 3 < last ? i + 3 : last;
        int i4 = i + 4 < last ? i + 4 : last;
        int i5 = i + 5 < last ? i + 5 : last;
        int i6 = i + 6 < last ? i + 6 : last;
        int i7 = i + 7 < last ? i + 7 : last;
        int s0 = csr[i],  s1 = csr[i1], s2 = csr[i2], s3 = csr[i3];
        int s4 = csr[i4], s5 = csr[i5], s6 = csr[i6], s7 = csr[i7];
        ushort4 v0 = *(const ushort4*)(msg + (long)s0 * STATE + jg);
        ushort4 v1 = *(const ushort4*)(msg + (long)s1 * STATE + jg);
        ushort4 v2 = *(const ushort4*)(msg + (long)s2 * STATE + jg);
        ushort4 v3 = *(const ushort4*)(msg + (long)s3 * STATE + jg);
        ushort4 v4 = *(const ushort4*)(msg + (long)s4 * STATE + jg);
        ushort4 v5 = *(const ushort4*)(msg + (long)s5 * STATE + jg);
        ushort4 v6 = *(const ushort4*)(msg + (long)s6 * STATE + jg);
        ushort4 v7 = *(const ushort4*)(msg + (long)s7 * STATE + jg);
        float m1 = (i + 1 < end) ? 1.f : 0.f;
        float m2 = (i + 2 < end) ? 1.f : 0.f;
        float m3 = (i + 3 < end) ? 1.f : 0.f;
        float m4 = (i + 4 < end) ? 1.f : 0.f;
        float m5 = (i + 5 < end) ? 1.f : 0.f;
        float m6 = (i + 6 < end) ? 1.f : 0.f;
        float m7 = (i + 7 < end) ? 1.f : 0.f;
        acc.x += bf2f(v0.x);      acc.y += bf2f(v0.y);      acc.z += bf2f(v0.z);      acc.w += bf2f(v0.w);
        acc.x += bf2f(v1.x) * m1; acc.y += bf2f(v1.y) * m1; acc.z += bf2f(v1.z) * m1; acc.w += bf2f(v1.w) * m1;
        acc.x += bf2f(v2.x) * m2; acc.y += bf2f(v2.y) * m2; acc.z += bf2f(v2.z) * m2; acc.w += bf2f(v2.w) * m2;
        acc.x += bf2f(v3.x) * m3; acc.y += bf2f(v3.y) * m3; acc.z += bf2f(v3.z) * m3; acc.w += bf2f(v3.w) * m3;
        acc.x += bf2f(v4.x) * m4; acc.y += bf2f(v4.y) * m4; acc.z += bf2f(v4.z) * m4; acc.w += bf2f(v4.w) * m4;
        acc.x += bf2f(v5.x) * m5; acc.y += bf2f(v5.y) * m5; acc.z += bf2f(v5.z) * m5; acc.w += bf2f(v5.w) * m5;
        acc.x += bf2f(v6.x) * m6; acc.y += bf2f(v6.y) * m6; acc.z += bf2f(v6.z) * m6; acc.w += bf2f(v6.w) * m6;
        acc.x += bf2f(v7.x) * m7; acc.y += bf2f(v7.y) * m7; acc.z += bf2f(v7.z) * m7; acc.w += bf2f(v7.w) * m7;
    }
    return acc;
}

__device__ __forceinline__ void store_bf4(bfraw* p, float a, float b, float c, float d) {
    ushort4 u; u.x = f2bf(a); u.y = f2bf(b); u.z = f2bf(c); u.w = f2bf(d);
    *(ushort4*)p = u;
}

// ---------------------------------------------------------------------------
// Fused: state = relu(x @ inW + inb); message(bf16) = relu(state @ msgW + msgb)
// Weights read straight from global (L1/L2-hot, shared by all blocks) —
// LDS holds only the x / state tiles so occupancy stays wave-slot-limited.
// ---------------------------------------------------------------------------
__global__ __launch_bounds__(256) void k_in_msg(
    const float* __restrict__ x, const float* __restrict__ inW, const float* __restrict__ inb,
    const float* __restrict__ msgW, const float* __restrict__ msgb,
    float* __restrict__ state, bfraw* __restrict__ message)
{
    __shared__ float sx[16 * 132];
    __shared__ float ss[16 * 68];

    const int ns = threadIdx.x >> 4;
    const int jg = (threadIdx.x & 15) << 2;

    for (int base = blockIdx.x * 16; base < NODES; base += gridDim.x * 16) {
        __syncthreads();
        for (int i = threadIdx.x; i < 512; i += 256) {
            int row = i >> 5, q = (i & 31) << 2;
            int n = base + row;
            float4 v = make_float4(0.f, 0.f, 0.f, 0.f);
            if (n < NODES) v = *(const float4*)(x + (long)n * FEAT + q);
            *(float4*)(sx + row * 132 + q) = v;
        }
        __syncthreads();

        const int n = base + ns;
        float4 b0 = *(const float4*)(inb + jg);
        float a0 = b0.x, a1 = b0.y, a2 = b0.z, a3 = b0.w;
        const float* xr = sx + ns * 132;
        #pragma unroll 8
        for (int k = 0; k < FEAT; k++) {
            float xv = xr[k];
            float4 w = *(const float4*)(inW + k * STATE + jg);
            a0 += xv * w.x; a1 += xv * w.y; a2 += xv * w.z; a3 += xv * w.w;
        }
        a0 = fmaxf(a0, 0.f); a1 = fmaxf(a1, 0.f); a2 = fmaxf(a2, 0.f); a3 = fmaxf(a3, 0.f);
        if (n < NODES) *(float4*)(state + (long)n * STATE + jg) = make_float4(a0, a1, a2, a3);
        *(float4*)(ss + ns * 68 + jg) = make_float4(a0, a1, a2, a3);
        __syncthreads();

        float4 b1 = *(const float4*)(msgb + jg);
        float m0 = b1.x, m1 = b1.y, m2 = b1.z, m3 = b1.w;
        const float* sr = ss + ns * 68;
        #pragma unroll 8
        for (int k = 0; k < STATE; k++) {
            float sv = sr[k];
            float4 w = *(const float4*)(msgW + k * STATE + jg);
            m0 += sv * w.x; m1 += sv * w.y; m2 += sv * w.z; m3 += sv * w.w;
        }
        m0 = fmaxf(m0, 0.f); m1 = fmaxf(m1, 0.f); m2 = fmaxf(m2, 0.f); m3 = fmaxf(m3, 0.f);
        if (n < NODES) store_bf4(message + (long)n * STATE + jg, m0, m1, m2, m3);
    }
}

// ---------------------------------------------------------------------------
// CSR build (flat, dst-major)
// ---------------------------------------------------------------------------
__global__ __launch_bounds__(256) void k_hist(const int* __restrict__ ei, int* __restrict__ deg)
{
    int e = blockIdx.x * 256 + threadIdx.x;
    if (e < EDGES) atomicAdd(&deg[ei[EDGES + e]], 1);
}

__global__ __launch_bounds__(1024) void k_scan(const int* __restrict__ deg,
                                               int* __restrict__ rowptr,
                                               int* __restrict__ cursor)
{
    __shared__ int wsum[16];
    __shared__ int carry;
    const int tid = threadIdx.x;
    const int lane = tid & 63, wid = tid >> 6;
    if (tid == 0) carry = 0;
    __syncthreads();
    for (int base = 0; base < NODES; base += 1024) {
        int v = (base + tid < NODES) ? deg[base + tid] : 0;
        int incl = v;
        #pragma unroll
        for (int off = 1; off < 64; off <<= 1) {
            int t = __shfl_up(incl, off, 64);
            if (lane >= off) incl += t;
        }
        if (lane == 63) wsum[wid] = incl;
        __syncthreads();
        if (tid < 16) {
            int t = wsum[tid];
            #pragma unroll
            for (int off = 1; off < 16; off <<= 1) {
                int u = __shfl_up(t, off, 64);
                if (tid >= off) t += u;
            }
            wsum[tid] = t;
        }
        __syncthreads();
        int wbase = (wid == 0) ? 0 : wsum[wid - 1];
        int excl = carry + wbase + incl - v;
        if (base + tid < NODES) { rowptr[base + tid] = excl; cursor[base + tid] = excl; }
        int tot = wsum[15];
        __syncthreads();
        if (tid == 0) carry += tot;
        __syncthreads();
    }
    if (tid == 0) rowptr[NODES] = carry;
}

__global__ __launch_bounds__(256) void k_fill(const int* __restrict__ ei,
                                              int* __restrict__ cursor,
                                              int* __restrict__ csr)
{
    int e = blockIdx.x * 256 + threadIdx.x;
    if (e < EDGES) {
        int src = ei[e];
        int dst = ei[EDGES + e];
        int slot = atomicAdd(&cursor[dst], 1);
        csr[slot] = src;
    }
}

// ---------------------------------------------------------------------------
// Pull aggregation (bf16 gather) fused with update + next message.
// LDS: only the two 16x68 tiles (~8.7 KB) -> 8 blocks/CU (wave-slot limit).
// ---------------------------------------------------------------------------
__global__ __launch_bounds__(256) void k_agg_upd_msg(
    const float* __restrict__ updW, const float* __restrict__ updb,
    const float* __restrict__ msgW, const float* __restrict__ msgb,
    const int* __restrict__ rowptr, const int* __restrict__ csr,
    const bfraw* __restrict__ msg_in,
    float* __restrict__ state, bfraw* __restrict__ msg_out)
{
    __shared__ float sa[16 * 68], ss[16 * 68];

    const int ns = threadIdx.x >> 4;
    const int jg = (threadIdx.x & 15) << 2;

    for (int base = blockIdx.x * 16; base < NODES; base += gridDim.x * 16) {
        const int n = base + ns;
        float4 acc = make_float4(0.f, 0.f, 0.f, 0.f);
        if (n < NODES) {
            int beg = rowptr[n], end = rowptr[n + 1];
            acc = gather_sum8(csr, msg_in, beg, end, jg);
        }
        __syncthreads();
        *(float4*)(sa + ns * 68 + jg) = acc;
        __syncthreads();

        float4 b0 = *(const float4*)(updb + jg);
        float a0 = b0.x, a1 = b0.y, a2 = b0.z, a3 = b0.w;
        const float* ar = sa + ns * 68;
        #pragma unroll 8
        for (int k = 0; k < STATE; k++) {
            float av = ar[k];
            float4 w = *(const float4*)(updW + k * STATE + jg);
            a0 += av * w.x; a1 += av * w.y; a2 += av * w.z; a3 += av * w.w;
        }
        a0 = fmaxf(a0, 0.f); a1 = fmaxf(a1, 0.f); a2 = fmaxf(a2, 0.f); a3 = fmaxf(a3, 0.f);
        float4 st = make_float4(0.f, 0.f, 0.f, 0.f);
        if (n < NODES) st = *(const float4*)(state + (long)n * STATE + jg);
        float s0 = st.x + a0, s1 = st.y + a1, s2 = st.z + a2, s3 = st.w + a3;
        if (n < NODES) *(float4*)(state + (long)n * STATE + jg) = make_float4(s0, s1, s2, s3);
        *(float4*)(ss + ns * 68 + jg) = make_float4(s0, s1, s2, s3);
        __syncthreads();

        float4 b1 = *(const float4*)(msgb + jg);
        float m0 = b1.x, m1 = b1.y, m2 = b1.z, m3 = b1.w;
        const float* sr = ss + ns * 68;
        #pragma unroll 8
        for (int k = 0; k < STATE; k++) {
            float sv = sr[k];
            float4 w = *(const float4*)(msgW + k * STATE + jg);
            m0 += sv * w.x; m1 += sv * w.y; m2 += sv * w.z; m3 += sv * w.w;
        }
        m0 = fmaxf(m0, 0.f); m1 = fmaxf(m1, 0.f); m2 = fmaxf(m2, 0.f); m3 = fmaxf(m3, 0.f);
        if (n < NODES) store_bf4(msg_out + (long)n * STATE + jg, m0, m1, m2, m3);
    }
}

// ---------------------------------------------------------------------------
// Last round: aggregation + update fused with graph pooling.
// ---------------------------------------------------------------------------
__global__ __launch_bounds__(256) void k_agg_upd_pool(
    const float* __restrict__ updW, const float* __restrict__ updb,
    const int* __restrict__ rowptr, const int* __restrict__ csr,
    const bfraw* __restrict__ msg_in,
    const float* __restrict__ state, const int* __restrict__ batch,
    float* __restrict__ gs)
{
    __shared__ float sa[16 * 68];

    const int ns = threadIdx.x >> 4;
    const int jg = (threadIdx.x & 15) << 2;

    for (int base = blockIdx.x * 16; base < NODES; base += gridDim.x * 16) {
        const int n = base + ns;
        float4 acc = make_float4(0.f, 0.f, 0.f, 0.f);
        if (n < NODES) {
            int beg = rowptr[n], end = rowptr[n + 1];
            acc = gather_sum8(csr, msg_in, beg, end, jg);
        }
        __syncthreads();
        *(float4*)(sa + ns * 68 + jg) = acc;
        __syncthreads();

        float4 b0 = *(const float4*)(updb + jg);
        float a0 = b0.x, a1 = b0.y, a2 = b0.z, a3 = b0.w;
        const float* ar = sa + ns * 68;
        #pragma unroll 8
        for (int k = 0; k < STATE; k++) {
            float av = ar[k];
            float4 w = *(const float4*)(updW + k * STATE + jg);
            a0 += av * w.x; a1 += av * w.y; a2 += av * w.z; a3 += av * w.w;
        }
        a0 = fmaxf(a0, 0.f); a1 = fmaxf(a1, 0.f); a2 = fmaxf(a2, 0.f); a3 = fmaxf(a3, 0.f);
        if (n < NODES) {
            float4 st = *(const float4*)(state + (long)n * STATE + jg);
            int g = batch[n];
            float* p = gs + (long)g * STATE + jg;
            atomicAdd(p + 0, st.x + a0);
            atomicAdd(p + 1, st.y + a1);
            atomicAdd(p + 2, st.z + a2);
            atomicAdd(p + 3, st.w + a3);
        }
        __syncthreads();
    }
}

// ---------------------------------------------------------------------------
// mean = gs@meanW+b ; std = exp(0.5*clip(gs@lvW+b, -20, 2)) -> out[2,256,32]
// ---------------------------------------------------------------------------
__global__ __launch_bounds__(64) void k_final(
    const float* __restrict__ gs,
    const float* __restrict__ meanW, const float* __restrict__ meanb,
    const float* __restrict__ lvW, const float* __restrict__ lvb,
    float* __restrict__ out)
{
    __shared__ float row[STATE];
    const int g = blockIdx.x;
    const int j = threadIdx.x;
    row[j] = gs[g * STATE + j];
    __syncthreads();
    if (j < M_OUT) {
        float acc = meanb[j];
        #pragma unroll
        for (int k = 0; k < STATE; k++) acc += row[k] * meanW[k * M_OUT + j];
        out[g * M_OUT + j] = acc;
    } else {
        int jj = j - M_OUT;
        float acc = lvb[jj];
        #pragma unroll
        for (int k = 0; k < STATE; k++) acc += row[k] * lvW[k * M_OUT + jj];
        acc = fminf(fmaxf(acc, -20.f), 2.f);
        out[GRAPHS * M_OUT + g * M_OUT + jj] = expf(0.5f * acc);
    }
}

extern "C" void kernel_launch(void* const* d_in, const int* in_sizes, int n_in,
                              void* d_out, int out_size, void* d_ws, size_t ws_size,
                              hipStream_t stream) {
    const float* x     = (const float*)d_in[0];
    const int*   ei    = (const int*)d_in[1];   // [2, E]: row0 = src (gather), row1 = dst (scatter)
    const int*   batch = (const int*)d_in[2];
    const float* inW   = (const float*)d_in[3];
    const float* inb   = (const float*)d_in[4];
    const float* msgW  = (const float*)d_in[5]; // [4,64,64]
    const float* msgb  = (const float*)d_in[6]; // [4,64]
    const float* updW  = (const float*)d_in[7];
    const float* updb  = (const float*)d_in[8];
    const float* meanW = (const float*)d_in[9];
    const float* meanb = (const float*)d_in[10];
    const float* lvW   = (const float*)d_in[11];
    const float* lvb   = (const float*)d_in[12];
    float* out = (float*)d_out;

    const size_t NS  = (size_t)NODES * STATE * sizeof(float); // 12.8 MB (state)
    const size_t NSH = (size_t)NODES * STATE * sizeof(bfraw); //  6.4 MB (bf16 messages)
    char* ws = (char*)d_ws;
    size_t off = 0;
    auto alloc = [&](size_t bytes) { void* p = ws + off; off += (bytes + 255) & ~(size_t)255; return p; };
    float* state   = (float*)alloc(NS);
    bfraw* msgA    = (bfraw*)alloc(NSH);
    bfraw* msgB    = (bfraw*)alloc(NSH);
    float* gs      = (float*)alloc((size_t)GRAPHS * STATE * sizeof(float));
    int*   deg     = (int*)alloc((size_t)NODES * sizeof(int));
    int*   rowptr  = (int*)alloc((size_t)(NODES + 1) * sizeof(int));
    int*   cursor  = (int*)alloc((size_t)NODES * sizeof(int));
    int*   csr     = (int*)alloc((size_t)EDGES * sizeof(int));

    hipMemsetAsync(deg, 0, (size_t)NODES * sizeof(int), stream);
    hipMemsetAsync(gs, 0, (size_t)GRAPHS * STATE * sizeof(float), stream);

    k_hist<<<(EDGES + 255) / 256, 256, 0, stream>>>(ei, deg);
    k_scan<<<1, 1024, 0, stream>>>(deg, rowptr, cursor);
    k_fill<<<(EDGES + 255) / 256, 256, 0, stream>>>(ei, cursor, csr);

    k_in_msg<<<NTILES, 256, 0, stream>>>(x, inW, inb, msgW, msgb, state, msgA);

    bfraw* mi = msgA; bfraw* mo = msgB;
    for (int r = 0; r < ROUNDS - 1; r++) {
        k_agg_upd_msg<<<NTILES, 256, 0, stream>>>(
            updW + r * STATE * STATE, updb + r * STATE,
            msgW + (r + 1) * STATE * STATE, msgb + (r + 1) * STATE,
            rowptr, csr, mi, state, mo);
        bfraw* t = mi; mi = mo; mo = t;
    }
    k_agg_upd_pool<<<NTILES, 256, 0, stream>>>(
        updW + (ROUNDS - 1) * STATE * STATE, updb + (ROUNDS - 1) * STATE,
        rowptr, csr, mi, state, batch, gs);

    k_final<<<GRAPHS, 64, 0, stream>>>(gs, meanW, meanb, lvW, lvb, out);
}

// Round 7
// 532.237 us; speedup vs baseline: 1.2001x; 1.2001x over previous
//
#include <hip/hip_runtime.h>
#include <math.h>

#define NODES  50000
#define EDGES  800000
#define GRAPHS 256
#define FEAT   128
#define STATE  64
#define M_OUT  32
#define ROUNDS 4
#define NTILES ((NODES + 15) / 16)
#define HALF   32                      // features per plane
#define PLANE  ((long)NODES * HALF)    // bf16 elements per plane (3.2 MB)

typedef unsigned short bfraw;

__device__ __forceinline__ float bf2f(bfraw u) {
    union { unsigned int i; float f; } v; v.i = ((unsigned int)u) << 16; return v.f;
}
__device__ __forceinline__ bfraw f2bf(float f) {
    union { float f; unsigned int i; } v; v.f = f;
    unsigned int r = v.i + 0x7FFF + ((v.i >> 16) & 1); // round-nearest-even
    return (bfraw)(r >> 16);
}
__device__ __forceinline__ void store_bf4(bfraw* p, float a, float b, float c, float d) {
    ushort4 u; u.x = f2bf(a); u.y = f2bf(b); u.z = f2bf(c); u.w = f2bf(d);
    *(ushort4*)p = u;
}

// ---------------------------------------------------------------------------
// 8-deep gather over one 3.2MB bf16 plane (row stride = 32 feats).
// Tail indices clamped to end-1, masked by 0-multiplier.
// ---------------------------------------------------------------------------
__device__ __forceinline__ float4 gather_sum8_p(const int* __restrict__ csr,
                                                const bfraw* __restrict__ plane,
                                                int beg, int end, int jg)
{
    float4 acc = make_float4(0.f, 0.f, 0.f, 0.f);
    for (int i = beg; i < end; i += 8) {
        int last = end - 1;
        int i1 = i + 1 < last ? i + 1 : last;
        int i2 = i + 2 < last ? i + 2 : last;
        int i3 = i + 3 < last ? i + 3 : last;
        int i4 = i + 4 < last ? i + 4 : last;
        int i5 = i + 5 < last ? i + 5 : last;
        int i6 = i + 6 < last ? i + 6 : last;
        int i7 = i + 7 < last ? i + 7 : last;
        int s0 = csr[i],  s1 = csr[i1], s2 = csr[i2], s3 = csr[i3];
        int s4 = csr[i4], s5 = csr[i5], s6 = csr[i6], s7 = csr[i7];
        ushort4 v0 = *(const ushort4*)(plane + (long)s0 * HALF + jg);
        ushort4 v1 = *(const ushort4*)(plane + (long)s1 * HALF + jg);
        ushort4 v2 = *(const ushort4*)(plane + (long)s2 * HALF + jg);
        ushort4 v3 = *(const ushort4*)(plane + (long)s3 * HALF + jg);
        ushort4 v4 = *(const ushort4*)(plane + (long)s4 * HALF + jg);
        ushort4 v5 = *(const ushort4*)(plane + (long)s5 * HALF + jg);
        ushort4 v6 = *(const ushort4*)(plane + (long)s6 * HALF + jg);
        ushort4 v7 = *(const ushort4*)(plane + (long)s7 * HALF + jg);
        float m1 = (i + 1 < end) ? 1.f : 0.f;
        float m2 = (i + 2 < end) ? 1.f : 0.f;
        float m3 = (i + 3 < end) ? 1.f : 0.f;
        float m4 = (i + 4 < end) ? 1.f : 0.f;
        float m5 = (i + 5 < end) ? 1.f : 0.f;
        float m6 = (i + 6 < end) ? 1.f : 0.f;
        float m7 = (i + 7 < end) ? 1.f : 0.f;
        acc.x += bf2f(v0.x);      acc.y += bf2f(v0.y);      acc.z += bf2f(v0.z);      acc.w += bf2f(v0.w);
        acc.x += bf2f(v1.x) * m1; acc.y += bf2f(v1.y) * m1; acc.z += bf2f(v1.z) * m1; acc.w += bf2f(v1.w) * m1;
        acc.x += bf2f(v2.x) * m2; acc.y += bf2f(v2.y) * m2; acc.z += bf2f(v2.z) * m2; acc.w += bf2f(v2.w) * m2;
        acc.x += bf2f(v3.x) * m3; acc.y += bf2f(v3.y) * m3; acc.z += bf2f(v3.z) * m3; acc.w += bf2f(v3.w) * m3;
        acc.x += bf2f(v4.x) * m4; acc.y += bf2f(v4.y) * m4; acc.z += bf2f(v4.z) * m4; acc.w += bf2f(v4.w) * m4;
        acc.x += bf2f(v5.x) * m5; acc.y += bf2f(v5.y) * m5; acc.z += bf2f(v5.z) * m5; acc.w += bf2f(v5.w) * m5;
        acc.x += bf2f(v6.x) * m6; acc.y += bf2f(v6.y) * m6; acc.z += bf2f(v6.z) * m6; acc.w += bf2f(v6.w) * m6;
        acc.x += bf2f(v7.x) * m7; acc.y += bf2f(v7.y) * m7; acc.z += bf2f(v7.z) * m7; acc.w += bf2f(v7.w) * m7;
    }
    return acc;
}

// ---------------------------------------------------------------------------
// Plane gather: agg_half[n][0..31] = sum over edges of plane[src].
// 8 lanes per node, 32 nodes per 256-thread block, NO barriers/LDS.
// While this dispatch runs the chip's random read set is one 3.2MB plane ->
// fits each XCD's 4MB L2 -> gathers are L2 hits after warm-up.
// ---------------------------------------------------------------------------
__global__ __launch_bounds__(256) void k_gather_half(
    const int* __restrict__ rowptr, const int* __restrict__ csr,
    const bfraw* __restrict__ plane, float* __restrict__ agg_half)
{
    int n = blockIdx.x * 32 + (threadIdx.x >> 3);
    if (n >= NODES) return;
    int jg = (threadIdx.x & 7) << 2;
    int beg = rowptr[n], end = rowptr[n + 1];
    float4 acc = gather_sum8_p(csr, plane, beg, end, jg);
    *(float4*)(agg_half + (long)n * HALF + jg) = acc;
}

// ---------------------------------------------------------------------------
// Fused: state = relu(x @ inW + inb); message planes = relu(state @ msgW + msgb)
// (round-5 structure: LDS weight staging, 16 nodes/block)
// ---------------------------------------------------------------------------
__global__ __launch_bounds__(256) void k_in_msg(
    const float* __restrict__ x, const float* __restrict__ inW, const float* __restrict__ inb,
    const float* __restrict__ msgW, const float* __restrict__ msgb,
    float* __restrict__ state, bfraw* __restrict__ msg0, bfraw* __restrict__ msg1)
{
    __shared__ float sInW[FEAT * STATE];
    __shared__ float sMsgW[STATE * STATE];
    __shared__ float sInb[STATE], sMsgb[STATE];
    __shared__ float sx[16 * 132];
    __shared__ float ss[16 * 68];

    for (int i = threadIdx.x; i < (FEAT * STATE) / 4; i += 256)
        *(float4*)(sInW + i * 4) = *(const float4*)(inW + i * 4);
    for (int i = threadIdx.x; i < (STATE * STATE) / 4; i += 256)
        *(float4*)(sMsgW + i * 4) = *(const float4*)(msgW + i * 4);
    if (threadIdx.x < STATE) {
        sInb[threadIdx.x]  = inb[threadIdx.x];
        sMsgb[threadIdx.x] = msgb[threadIdx.x];
    }

    const int ns = threadIdx.x >> 4;
    const int jg = (threadIdx.x & 15) << 2;

    for (int base = blockIdx.x * 16; base < NODES; base += gridDim.x * 16) {
        __syncthreads();
        for (int i = threadIdx.x; i < 512; i += 256) {
            int row = i >> 5, q = (i & 31) << 2;
            int n = base + row;
            float4 v = make_float4(0.f, 0.f, 0.f, 0.f);
            if (n < NODES) v = *(const float4*)(x + (long)n * FEAT + q);
            *(float4*)(sx + row * 132 + q) = v;
        }
        __syncthreads();

        const int n = base + ns;
        float a0 = sInb[jg], a1 = sInb[jg + 1], a2 = sInb[jg + 2], a3 = sInb[jg + 3];
        const float* xr = sx + ns * 132;
        #pragma unroll 8
        for (int k = 0; k < FEAT; k++) {
            float xv = xr[k];
            float4 w = *(const float4*)(sInW + k * STATE + jg);
            a0 += xv * w.x; a1 += xv * w.y; a2 += xv * w.z; a3 += xv * w.w;
        }
        a0 = fmaxf(a0, 0.f); a1 = fmaxf(a1, 0.f); a2 = fmaxf(a2, 0.f); a3 = fmaxf(a3, 0.f);
        if (n < NODES) *(float4*)(state + (long)n * STATE + jg) = make_float4(a0, a1, a2, a3);
        *(float4*)(ss + ns * 68 + jg) = make_float4(a0, a1, a2, a3);
        __syncthreads();

        float m0 = sMsgb[jg], m1 = sMsgb[jg + 1], m2 = sMsgb[jg + 2], m3 = sMsgb[jg + 3];
        const float* sr = ss + ns * 68;
        #pragma unroll 8
        for (int k = 0; k < STATE; k++) {
            float sv = sr[k];
            float4 w = *(const float4*)(sMsgW + k * STATE + jg);
            m0 += sv * w.x; m1 += sv * w.y; m2 += sv * w.z; m3 += sv * w.w;
        }
        m0 = fmaxf(m0, 0.f); m1 = fmaxf(m1, 0.f); m2 = fmaxf(m2, 0.f); m3 = fmaxf(m3, 0.f);
        if (n < NODES) {
            if (jg < HALF) store_bf4(msg0 + (long)n * HALF + jg, m0, m1, m2, m3);
            else           store_bf4(msg1 + (long)n * HALF + (jg - HALF), m0, m1, m2, m3);
        }
    }
}

// ---------------------------------------------------------------------------
// CSR build (flat, dst-major)
// ---------------------------------------------------------------------------
__global__ __launch_bounds__(256) void k_hist(const int* __restrict__ ei, int* __restrict__ deg)
{
    int e = blockIdx.x * 256 + threadIdx.x;
    if (e < EDGES) atomicAdd(&deg[ei[EDGES + e]], 1);
}

__global__ __launch_bounds__(1024) void k_scan(const int* __restrict__ deg,
                                               int* __restrict__ rowptr,
                                               int* __restrict__ cursor)
{
    __shared__ int wsum[16];
    __shared__ int carry;
    const int tid = threadIdx.x;
    const int lane = tid & 63, wid = tid >> 6;
    if (tid == 0) carry = 0;
    __syncthreads();
    for (int base = 0; base < NODES; base += 1024) {
        int v = (base + tid < NODES) ? deg[base + tid] : 0;
        int incl = v;
        #pragma unroll
        for (int off = 1; off < 64; off <<= 1) {
            int t = __shfl_up(incl, off, 64);
            if (lane >= off) incl += t;
        }
        if (lane == 63) wsum[wid] = incl;
        __syncthreads();
        if (tid < 16) {
            int t = wsum[tid];
            #pragma unroll
            for (int off = 1; off < 16; off <<= 1) {
                int u = __shfl_up(t, off, 64);
                if (tid >= off) t += u;
            }
            wsum[tid] = t;
        }
        __syncthreads();
        int wbase = (wid == 0) ? 0 : wsum[wid - 1];
        int excl = carry + wbase + incl - v;
        if (base + tid < NODES) { rowptr[base + tid] = excl; cursor[base + tid] = excl; }
        int tot = wsum[15];
        __syncthreads();
        if (tid == 0) carry += tot;
        __syncthreads();
    }
    if (tid == 0) rowptr[NODES] = carry;
}

__global__ __launch_bounds__(256) void k_fill(const int* __restrict__ ei,
                                              int* __restrict__ cursor,
                                              int* __restrict__ csr)
{
    int e = blockIdx.x * 256 + threadIdx.x;
    if (e < EDGES) {
        int src = ei[e];
        int dst = ei[EDGES + e];
        int slot = atomicAdd(&cursor[dst], 1);
        csr[slot] = src;
    }
}

// ---------------------------------------------------------------------------
// Streaming update + next-message: reads precomputed agg halves,
// state += relu(agg@updW+b); msg planes = relu(state@msgW+b)
// ---------------------------------------------------------------------------
__global__ __launch_bounds__(256) void k_upd_msg(
    const float* __restrict__ updW, const float* __restrict__ updb,
    const float* __restrict__ msgW, const float* __restrict__ msgb,
    const float* __restrict__ aggH0, const float* __restrict__ aggH1,
    float* __restrict__ state, bfraw* __restrict__ msg0, bfraw* __restrict__ msg1)
{
    __shared__ float sUpdW[STATE * STATE], sMsgW[STATE * STATE];
    __shared__ float sUpdb[STATE], sMsgb[STATE];
    __shared__ float sa[16 * 68], ss[16 * 68];

    for (int i = threadIdx.x; i < (STATE * STATE) / 4; i += 256) {
        *(float4*)(sUpdW + i * 4) = *(const float4*)(updW + i * 4);
        *(float4*)(sMsgW + i * 4) = *(const float4*)(msgW + i * 4);
    }
    if (threadIdx.x < STATE) {
        sUpdb[threadIdx.x] = updb[threadIdx.x];
        sMsgb[threadIdx.x] = msgb[threadIdx.x];
    }

    const int ns = threadIdx.x >> 4;
    const int jg = (threadIdx.x & 15) << 2;

    for (int base = blockIdx.x * 16; base < NODES; base += gridDim.x * 16) {
        __syncthreads();
        // stage agg tile: 16 nodes x 64 feats from the two half buffers
        {
            int row = threadIdx.x >> 4, q = (threadIdx.x & 15) << 2;
            int n = base + row;
            float4 v = make_float4(0.f, 0.f, 0.f, 0.f);
            if (n < NODES) {
                if (q < HALF) v = *(const float4*)(aggH0 + (long)n * HALF + q);
                else          v = *(const float4*)(aggH1 + (long)n * HALF + (q - HALF));
            }
            *(float4*)(sa + row * 68 + q) = v;
        }
        __syncthreads();

        const int n = base + ns;
        float a0 = sUpdb[jg], a1 = sUpdb[jg + 1], a2 = sUpdb[jg + 2], a3 = sUpdb[jg + 3];
        const float* ar = sa + ns * 68;
        #pragma unroll 8
        for (int k = 0; k < STATE; k++) {
            float av = ar[k];
            float4 w = *(const float4*)(sUpdW + k * STATE + jg);
            a0 += av * w.x; a1 += av * w.y; a2 += av * w.z; a3 += av * w.w;
        }
        a0 = fmaxf(a0, 0.f); a1 = fmaxf(a1, 0.f); a2 = fmaxf(a2, 0.f); a3 = fmaxf(a3, 0.f);
        float4 st = make_float4(0.f, 0.f, 0.f, 0.f);
        if (n < NODES) st = *(const float4*)(state + (long)n * STATE + jg);
        float s0 = st.x + a0, s1 = st.y + a1, s2 = st.z + a2, s3 = st.w + a3;
        if (n < NODES) *(float4*)(state + (long)n * STATE + jg) = make_float4(s0, s1, s2, s3);
        *(float4*)(ss + ns * 68 + jg) = make_float4(s0, s1, s2, s3);
        __syncthreads();

        float m0 = sMsgb[jg], m1 = sMsgb[jg + 1], m2 = sMsgb[jg + 2], m3 = sMsgb[jg + 3];
        const float* sr = ss + ns * 68;
        #pragma unroll 8
        for (int k = 0; k < STATE; k++) {
            float sv = sr[k];
            float4 w = *(const float4*)(sMsgW + k * STATE + jg);
            m0 += sv * w.x; m1 += sv * w.y; m2 += sv * w.z; m3 += sv * w.w;
        }
        m0 = fmaxf(m0, 0.f); m1 = fmaxf(m1, 0.f); m2 = fmaxf(m2, 0.f); m3 = fmaxf(m3, 0.f);
        if (n < NODES) {
            if (jg < HALF) store_bf4(msg0 + (long)n * HALF + jg, m0, m1, m2, m3);
            else           store_bf4(msg1 + (long)n * HALF + (jg - HALF), m0, m1, m2, m3);
        }
    }
}

// ---------------------------------------------------------------------------
// Last round: update fused with graph pooling (streaming agg read).
// ---------------------------------------------------------------------------
__global__ __launch_bounds__(256) void k_upd_pool(
    const float* __restrict__ updW, const float* __restrict__ updb,
    const float* __restrict__ aggH0, const float* __restrict__ aggH1,
    const float* __restrict__ state, const int* __restrict__ batch,
    float* __restrict__ gs)
{
    __shared__ float sUpdW[STATE * STATE];
    __shared__ float sUpdb[STATE];
    __shared__ float sa[16 * 68];

    for (int i = threadIdx.x; i < (STATE * STATE) / 4; i += 256)
        *(float4*)(sUpdW + i * 4) = *(const float4*)(updW + i * 4);
    if (threadIdx.x < STATE) sUpdb[threadIdx.x] = updb[threadIdx.x];

    const int ns = threadIdx.x >> 4;
    const int jg = (threadIdx.x & 15) << 2;

    for (int base = blockIdx.x * 16; base < NODES; base += gridDim.x * 16) {
        __syncthreads();
        {
            int row = threadIdx.x >> 4, q = (threadIdx.x & 15) << 2;
            int n = base + row;
            float4 v = make_float4(0.f, 0.f, 0.f, 0.f);
            if (n < NODES) {
                if (q < HALF) v = *(const float4*)(aggH0 + (long)n * HALF + q);
                else          v = *(const float4*)(aggH1 + (long)n * HALF + (q - HALF));
            }
            *(float4*)(sa + row * 68 + q) = v;
        }
        __syncthreads();

        const int n = base + ns;
        float a0 = sUpdb[jg], a1 = sUpdb[jg + 1], a2 = sUpdb[jg + 2], a3 = sUpdb[jg + 3];
        const float* ar = sa + ns * 68;
        #pragma unroll 8
        for (int k = 0; k < STATE; k++) {
            float av = ar[k];
            float4 w = *(const float4*)(sUpdW + k * STATE + jg);
            a0 += av * w.x; a1 += av * w.y; a2 += av * w.z; a3 += av * w.w;
        }
        a0 = fmaxf(a0, 0.f); a1 = fmaxf(a1, 0.f); a2 = fmaxf(a2, 0.f); a3 = fmaxf(a3, 0.f);
        if (n < NODES) {
            float4 st = *(const float4*)(state + (long)n * STATE + jg);
            int g = batch[n];
            float* p = gs + (long)g * STATE + jg;
            atomicAdd(p + 0, st.x + a0);
            atomicAdd(p + 1, st.y + a1);
            atomicAdd(p + 2, st.z + a2);
            atomicAdd(p + 3, st.w + a3);
        }
    }
}

// ---------------------------------------------------------------------------
// mean = gs@meanW+b ; std = exp(0.5*clip(gs@lvW+b, -20, 2)) -> out[2,256,32]
// ---------------------------------------------------------------------------
__global__ __launch_bounds__(64) void k_final(
    const float* __restrict__ gs,
    const float* __restrict__ meanW, const float* __restrict__ meanb,
    const float* __restrict__ lvW, const float* __restrict__ lvb,
    float* __restrict__ out)
{
    __shared__ float row[STATE];
    const int g = blockIdx.x;
    const int j = threadIdx.x;
    row[j] = gs[g * STATE + j];
    __syncthreads();
    if (j < M_OUT) {
        float acc = meanb[j];
        #pragma unroll
        for (int k = 0; k < STATE; k++) acc += row[k] * meanW[k * M_OUT + j];
        out[g * M_OUT + j] = acc;
    } else {
        int jj = j - M_OUT;
        float acc = lvb[jj];
        #pragma unroll
        for (int k = 0; k < STATE; k++) acc += row[k] * lvW[k * M_OUT + jj];
        acc = fminf(fmaxf(acc, -20.f), 2.f);
        out[GRAPHS * M_OUT + g * M_OUT + jj] = expf(0.5f * acc);
    }
}

extern "C" void kernel_launch(void* const* d_in, const int* in_sizes, int n_in,
                              void* d_out, int out_size, void* d_ws, size_t ws_size,
                              hipStream_t stream) {
    const float* x     = (const float*)d_in[0];
    const int*   ei    = (const int*)d_in[1];   // [2, E]: row0 = src (gather), row1 = dst (scatter)
    const int*   batch = (const int*)d_in[2];
    const float* inW   = (const float*)d_in[3];
    const float* inb   = (const float*)d_in[4];
    const float* msgW  = (const float*)d_in[5]; // [4,64,64]
    const float* msgb  = (const float*)d_in[6]; // [4,64]
    const float* updW  = (const float*)d_in[7];
    const float* updb  = (const float*)d_in[8];
    const float* meanW = (const float*)d_in[9];
    const float* meanb = (const float*)d_in[10];
    const float* lvW   = (const float*)d_in[11];
    const float* lvb   = (const float*)d_in[12];
    float* out = (float*)d_out;

    const size_t NS   = (size_t)NODES * STATE * sizeof(float);  // 12.8 MB state
    const size_t PLB  = (size_t)PLANE * sizeof(bfraw);          //  3.2 MB per bf16 plane
    const size_t AGH  = (size_t)NODES * HALF * sizeof(float);   //  6.4 MB per agg half
    char* ws = (char*)d_ws;
    size_t off = 0;
    auto alloc = [&](size_t bytes) { void* p = ws + off; off += (bytes + 255) & ~(size_t)255; return p; };
    float* state  = (float*)alloc(NS);
    bfraw* msgA0  = (bfraw*)alloc(PLB);
    bfraw* msgA1  = (bfraw*)alloc(PLB);
    bfraw* msgB0  = (bfraw*)alloc(PLB);
    bfraw* msgB1  = (bfraw*)alloc(PLB);
    float* aggH0  = (float*)alloc(AGH);
    float* aggH1  = (float*)alloc(AGH);
    float* gs     = (float*)alloc((size_t)GRAPHS * STATE * sizeof(float));
    int*   deg    = (int*)alloc((size_t)NODES * sizeof(int));
    int*   rowptr = (int*)alloc((size_t)(NODES + 1) * sizeof(int));
    int*   cursor = (int*)alloc((size_t)NODES * sizeof(int));
    int*   csr    = (int*)alloc((size_t)EDGES * sizeof(int));

    hipMemsetAsync(deg, 0, (size_t)NODES * sizeof(int), stream);
    hipMemsetAsync(gs, 0, (size_t)GRAPHS * STATE * sizeof(float), stream);

    k_hist<<<(EDGES + 255) / 256, 256, 0, stream>>>(ei, deg);
    k_scan<<<1, 1024, 0, stream>>>(deg, rowptr, cursor);
    k_fill<<<(EDGES + 255) / 256, 256, 0, stream>>>(ei, cursor, csr);

    k_in_msg<<<NTILES, 256, 0, stream>>>(x, inW, inb, msgW, msgb, state, msgA0, msgA1);

    const int GG = (NODES + 31) / 32; // gather grid: 32 nodes/block, 8 lanes/node
    bfraw *mi0 = msgA0, *mi1 = msgA1, *mo0 = msgB0, *mo1 = msgB1;
    for (int r = 0; r < ROUNDS; r++) {
        // two plane-resident gather dispatches (chip-wide 3.2MB read set each)
        k_gather_half<<<GG, 256, 0, stream>>>(rowptr, csr, mi0, aggH0);
        k_gather_half<<<GG, 256, 0, stream>>>(rowptr, csr, mi1, aggH1);
        if (r < ROUNDS - 1) {
            k_upd_msg<<<NTILES, 256, 0, stream>>>(
                updW + r * STATE * STATE, updb + r * STATE,
                msgW + (r + 1) * STATE * STATE, msgb + (r + 1) * STATE,
                aggH0, aggH1, state, mo0, mo1);
            bfraw* t0 = mi0; mi0 = mo0; mo0 = t0;
            bfraw* t1 = mi1; mi1 = mo1; mo1 = t1;
        } else {
            k_upd_pool<<<NTILES, 256, 0, stream>>>(
                updW + r * STATE * STATE, updb + r * STATE,
                aggH0, aggH1, state, batch, gs);
        }
    }

    k_final<<<GRAPHS, 64, 0, stream>>>(gs, meanW, meanb, lvW, lvb, out);
}

// Round 8
// 412.209 us; speedup vs baseline: 1.5495x; 1.2912x over previous
//
#include <hip/hip_runtime.h>
#include <math.h>

#define NODES  50000
#define EDGES  800000
#define GRAPHS 256
#define FEAT   128
#define STATE  64
#define M_OUT  32
#define ROUNDS 4
#define NTILES (NODES / 16)            // 3125, exact (no partial tiles)
#define HALF   32                      // features per plane
#define PLANE  ((long)NODES * HALF)    // bf16 elements per plane (3.2 MB)
#define SCAN_BLOCKS ((NODES + 1023) / 1024)  // 49

typedef unsigned short bfraw;

__device__ __forceinline__ float bf2f(bfraw u) {
    union { unsigned int i; float f; } v; v.i = ((unsigned int)u) << 16; return v.f;
}
__device__ __forceinline__ bfraw f2bf(float f) {
    union { float f; unsigned int i; } v; v.f = f;
    unsigned int r = v.i + 0x7FFF + ((v.i >> 16) & 1); // round-nearest-even
    return (bfraw)(r >> 16);
}
__device__ __forceinline__ void store_bf4(bfraw* p, float a, float b, float c, float d) {
    ushort4 u; u.x = f2bf(a); u.y = f2bf(b); u.z = f2bf(c); u.w = f2bf(d);
    *(ushort4*)p = u;
}

// ---------------------------------------------------------------------------
// 8-deep gather over one 3.2MB bf16 plane (row stride = 32 feats).
// ---------------------------------------------------------------------------
__device__ __forceinline__ float4 gather_sum8_p(const int* __restrict__ csr,
                                                const bfraw* __restrict__ plane,
                                                int beg, int end, int jg)
{
    float4 acc = make_float4(0.f, 0.f, 0.f, 0.f);
    for (int i = beg; i < end; i += 8) {
        int last = end - 1;
        int i1 = i + 1 < last ? i + 1 : last;
        int i2 = i + 2 < last ? i + 2 : last;
        int i3 = i + 3 < last ? i + 3 : last;
        int i4 = i + 4 < last ? i + 4 : last;
        int i5 = i + 5 < last ? i + 5 : last;
        int i6 = i + 6 < last ? i + 6 : last;
        int i7 = i + 7 < last ? i + 7 : last;
        int s0 = csr[i],  s1 = csr[i1], s2 = csr[i2], s3 = csr[i3];
        int s4 = csr[i4], s5 = csr[i5], s6 = csr[i6], s7 = csr[i7];
        ushort4 v0 = *(const ushort4*)(plane + (long)s0 * HALF + jg);
        ushort4 v1 = *(const ushort4*)(plane + (long)s1 * HALF + jg);
        ushort4 v2 = *(const ushort4*)(plane + (long)s2 * HALF + jg);
        ushort4 v3 = *(const ushort4*)(plane + (long)s3 * HALF + jg);
        ushort4 v4 = *(const ushort4*)(plane + (long)s4 * HALF + jg);
        ushort4 v5 = *(const ushort4*)(plane + (long)s5 * HALF + jg);
        ushort4 v6 = *(const ushort4*)(plane + (long)s6 * HALF + jg);
        ushort4 v7 = *(const ushort4*)(plane + (long)s7 * HALF + jg);
        float m1 = (i + 1 < end) ? 1.f : 0.f;
        float m2 = (i + 2 < end) ? 1.f : 0.f;
        float m3 = (i + 3 < end) ? 1.f : 0.f;
        float m4 = (i + 4 < end) ? 1.f : 0.f;
        float m5 = (i + 5 < end) ? 1.f : 0.f;
        float m6 = (i + 6 < end) ? 1.f : 0.f;
        float m7 = (i + 7 < end) ? 1.f : 0.f;
        acc.x += bf2f(v0.x);      acc.y += bf2f(v0.y);      acc.z += bf2f(v0.z);      acc.w += bf2f(v0.w);
        acc.x += bf2f(v1.x) * m1; acc.y += bf2f(v1.y) * m1; acc.z += bf2f(v1.z) * m1; acc.w += bf2f(v1.w) * m1;
        acc.x += bf2f(v2.x) * m2; acc.y += bf2f(v2.y) * m2; acc.z += bf2f(v2.z) * m2; acc.w += bf2f(v2.w) * m2;
        acc.x += bf2f(v3.x) * m3; acc.y += bf2f(v3.y) * m3; acc.z += bf2f(v3.z) * m3; acc.w += bf2f(v3.w) * m3;
        acc.x += bf2f(v4.x) * m4; acc.y += bf2f(v4.y) * m4; acc.z += bf2f(v4.z) * m4; acc.w += bf2f(v4.w) * m4;
        acc.x += bf2f(v5.x) * m5; acc.y += bf2f(v5.y) * m5; acc.z += bf2f(v5.z) * m5; acc.w += bf2f(v5.w) * m5;
        acc.x += bf2f(v6.x) * m6; acc.y += bf2f(v6.y) * m6; acc.z += bf2f(v6.z) * m6; acc.w += bf2f(v6.w) * m6;
        acc.x += bf2f(v7.x) * m7; acc.y += bf2f(v7.y) * m7; acc.z += bf2f(v7.z) * m7; acc.w += bf2f(v7.w) * m7;
    }
    return acc;
}

// ---------------------------------------------------------------------------
// Plane gather: agg_half[n][0..31] = sum over edges of plane[src].
// 8 lanes per node, 32 nodes per block, NO barriers/LDS. Chip-wide read set
// during this dispatch = one 3.2MB plane -> per-XCD-L2 resident.
// ---------------------------------------------------------------------------
__global__ __launch_bounds__(256) void k_gather_half(
    const int* __restrict__ rowptr, const int* __restrict__ csr,
    const bfraw* __restrict__ plane, float* __restrict__ agg_half)
{
    int n = blockIdx.x * 32 + (threadIdx.x >> 3);
    if (n >= NODES) return;
    int jg = (threadIdx.x & 7) << 2;
    int beg = rowptr[n], end = rowptr[n + 1];
    float4 acc = gather_sum8_p(csr, plane, beg, end, jg);
    *(float4*)(agg_half + (long)n * HALF + jg) = acc;
}

// ---------------------------------------------------------------------------
// Fused: state = relu(x @ inW + inb); message planes = relu(state @ msgW + msgb)
// ---------------------------------------------------------------------------
__global__ __launch_bounds__(256) void k_in_msg(
    const float* __restrict__ x, const float* __restrict__ inW, const float* __restrict__ inb,
    const float* __restrict__ msgW, const float* __restrict__ msgb,
    float* __restrict__ state, bfraw* __restrict__ msg0, bfraw* __restrict__ msg1)
{
    __shared__ float sInW[FEAT * STATE];
    __shared__ float sMsgW[STATE * STATE];
    __shared__ float sInb[STATE], sMsgb[STATE];
    __shared__ float sx[16 * 132];
    __shared__ float ss[16 * 68];

    for (int i = threadIdx.x; i < (FEAT * STATE) / 4; i += 256)
        *(float4*)(sInW + i * 4) = *(const float4*)(inW + i * 4);
    for (int i = threadIdx.x; i < (STATE * STATE) / 4; i += 256)
        *(float4*)(sMsgW + i * 4) = *(const float4*)(msgW + i * 4);
    if (threadIdx.x < STATE) {
        sInb[threadIdx.x]  = inb[threadIdx.x];
        sMsgb[threadIdx.x] = msgb[threadIdx.x];
    }
    __syncthreads();

    const int ns = threadIdx.x >> 4;
    const int jg = (threadIdx.x & 15) << 2;
    const int base = blockIdx.x * 16;
    const int n = base + ns;

    for (int i = threadIdx.x; i < 512; i += 256) {
        int row = i >> 5, q = (i & 31) << 2;
        *(float4*)(sx + row * 132 + q) = *(const float4*)(x + (long)(base + row) * FEAT + q);
    }
    __syncthreads();

    float a0 = sInb[jg], a1 = sInb[jg + 1], a2 = sInb[jg + 2], a3 = sInb[jg + 3];
    const float* xr = sx + ns * 132;
    #pragma unroll 8
    for (int k = 0; k < FEAT; k++) {
        float xv = xr[k];
        float4 w = *(const float4*)(sInW + k * STATE + jg);
        a0 += xv * w.x; a1 += xv * w.y; a2 += xv * w.z; a3 += xv * w.w;
    }
    a0 = fmaxf(a0, 0.f); a1 = fmaxf(a1, 0.f); a2 = fmaxf(a2, 0.f); a3 = fmaxf(a3, 0.f);
    *(float4*)(state + (long)n * STATE + jg) = make_float4(a0, a1, a2, a3);
    *(float4*)(ss + ns * 68 + jg) = make_float4(a0, a1, a2, a3);
    __syncthreads();

    float m0 = sMsgb[jg], m1 = sMsgb[jg + 1], m2 = sMsgb[jg + 2], m3 = sMsgb[jg + 3];
    const float* sr = ss + ns * 68;
    #pragma unroll 8
    for (int k = 0; k < STATE; k++) {
        float sv = sr[k];
        float4 w = *(const float4*)(sMsgW + k * STATE + jg);
        m0 += sv * w.x; m1 += sv * w.y; m2 += sv * w.z; m3 += sv * w.w;
    }
    m0 = fmaxf(m0, 0.f); m1 = fmaxf(m1, 0.f); m2 = fmaxf(m2, 0.f); m3 = fmaxf(m3, 0.f);
    if (jg < HALF) store_bf4(msg0 + (long)n * HALF + jg, m0, m1, m2, m3);
    else           store_bf4(msg1 + (long)n * HALF + (jg - HALF), m0, m1, m2, m3);
}

// ---------------------------------------------------------------------------
// CSR build: histogram + hierarchical scan + fill
// ---------------------------------------------------------------------------
__global__ __launch_bounds__(256) void k_hist(const int* __restrict__ ei, int* __restrict__ deg)
{
    int e = blockIdx.x * 256 + threadIdx.x;
    if (e < EDGES) atomicAdd(&deg[ei[EDGES + e]], 1);
}

// per-1024-chunk exclusive scan; bsum[b] = chunk total
__global__ __launch_bounds__(1024) void k_scan1(const int* __restrict__ deg,
                                                int* __restrict__ part, int* __restrict__ bsum)
{
    __shared__ int wsum[16];
    const int tid = threadIdx.x, lane = tid & 63, wid = tid >> 6;
    int n = blockIdx.x * 1024 + tid;
    int v = (n < NODES) ? deg[n] : 0;
    int incl = v;
    #pragma unroll
    for (int off = 1; off < 64; off <<= 1) {
        int t = __shfl_up(incl, off, 64);
        if (lane >= off) incl += t;
    }
    if (lane == 63) wsum[wid] = incl;
    __syncthreads();
    if (tid < 16) {
        int t = wsum[tid];
        #pragma unroll
        for (int off = 1; off < 16; off <<= 1) {
            int u = __shfl_up(t, off, 64);
            if (tid >= off) t += u;
        }
        wsum[tid] = t;
    }
    __syncthreads();
    int wbase = (wid == 0) ? 0 : wsum[wid - 1];
    if (n < NODES) part[n] = wbase + incl - v;
    if (tid == 0) bsum[blockIdx.x] = wsum[15];
}

// exclusive scan of the 49 chunk totals (single wave)
__global__ __launch_bounds__(64) void k_scan2(const int* __restrict__ bsum, int* __restrict__ bcarry)
{
    int t = threadIdx.x;
    int v = (t < SCAN_BLOCKS) ? bsum[t] : 0;
    int incl = v;
    #pragma unroll
    for (int off = 1; off < 64; off <<= 1) {
        int u = __shfl_up(incl, off, 64);
        if (t >= off) incl += u;
    }
    if (t < SCAN_BLOCKS) bcarry[t] = incl - v;
}

__global__ __launch_bounds__(256) void k_scan3(const int* __restrict__ part,
                                               const int* __restrict__ bcarry,
                                               int* __restrict__ rowptr, int* __restrict__ cursor)
{
    int n = blockIdx.x * 256 + threadIdx.x;
    if (n < NODES) {
        int r = part[n] + bcarry[n >> 10];
        rowptr[n] = r; cursor[n] = r;
    }
    if (n == 0) rowptr[NODES] = EDGES;
}

__global__ __launch_bounds__(256) void k_fill(const int* __restrict__ ei,
                                              int* __restrict__ cursor,
                                              int* __restrict__ csr)
{
    int e = blockIdx.x * 256 + threadIdx.x;
    if (e < EDGES) {
        int src = ei[e];
        int dst = ei[EDGES + e];
        int slot = atomicAdd(&cursor[dst], 1);
        csr[slot] = src;
    }
}

// ---------------------------------------------------------------------------
// Streaming update + next-message.
// ---------------------------------------------------------------------------
__global__ __launch_bounds__(256) void k_upd_msg(
    const float* __restrict__ updW, const float* __restrict__ updb,
    const float* __restrict__ msgW, const float* __restrict__ msgb,
    const float* __restrict__ aggH0, const float* __restrict__ aggH1,
    float* __restrict__ state, bfraw* __restrict__ msg0, bfraw* __restrict__ msg1)
{
    __shared__ float sUpdW[STATE * STATE], sMsgW[STATE * STATE];
    __shared__ float sUpdb[STATE], sMsgb[STATE];
    __shared__ float sa[16 * 68], ss[16 * 68];

    for (int i = threadIdx.x; i < (STATE * STATE) / 4; i += 256) {
        *(float4*)(sUpdW + i * 4) = *(const float4*)(updW + i * 4);
        *(float4*)(sMsgW + i * 4) = *(const float4*)(msgW + i * 4);
    }
    if (threadIdx.x < STATE) {
        sUpdb[threadIdx.x] = updb[threadIdx.x];
        sMsgb[threadIdx.x] = msgb[threadIdx.x];
    }

    const int ns = threadIdx.x >> 4;
    const int jg = (threadIdx.x & 15) << 2;
    const int base = blockIdx.x * 16;
    const int n = base + ns;

    {
        int row = threadIdx.x >> 4, q = (threadIdx.x & 15) << 2;
        int nn = base + row;
        float4 v;
        if (q < HALF) v = *(const float4*)(aggH0 + (long)nn * HALF + q);
        else          v = *(const float4*)(aggH1 + (long)nn * HALF + (q - HALF));
        *(float4*)(sa + row * 68 + q) = v;
    }
    __syncthreads();

    float a0 = sUpdb[jg], a1 = sUpdb[jg + 1], a2 = sUpdb[jg + 2], a3 = sUpdb[jg + 3];
    const float* ar = sa + ns * 68;
    #pragma unroll 8
    for (int k = 0; k < STATE; k++) {
        float av = ar[k];
        float4 w = *(const float4*)(sUpdW + k * STATE + jg);
        a0 += av * w.x; a1 += av * w.y; a2 += av * w.z; a3 += av * w.w;
    }
    a0 = fmaxf(a0, 0.f); a1 = fmaxf(a1, 0.f); a2 = fmaxf(a2, 0.f); a3 = fmaxf(a3, 0.f);
    float4 st = *(const float4*)(state + (long)n * STATE + jg);
    float s0 = st.x + a0, s1 = st.y + a1, s2 = st.z + a2, s3 = st.w + a3;
    *(float4*)(state + (long)n * STATE + jg) = make_float4(s0, s1, s2, s3);
    *(float4*)(ss + ns * 68 + jg) = make_float4(s0, s1, s2, s3);
    __syncthreads();

    float m0 = sMsgb[jg], m1 = sMsgb[jg + 1], m2 = sMsgb[jg + 2], m3 = sMsgb[jg + 3];
    const float* sr = ss + ns * 68;
    #pragma unroll 8
    for (int k = 0; k < STATE; k++) {
        float sv = sr[k];
        float4 w = *(const float4*)(sMsgW + k * STATE + jg);
        m0 += sv * w.x; m1 += sv * w.y; m2 += sv * w.z; m3 += sv * w.w;
    }
    m0 = fmaxf(m0, 0.f); m1 = fmaxf(m1, 0.f); m2 = fmaxf(m2, 0.f); m3 = fmaxf(m3, 0.f);
    if (jg < HALF) store_bf4(msg0 + (long)n * HALF + jg, m0, m1, m2, m3);
    else           store_bf4(msg1 + (long)n * HALF + (jg - HALF), m0, m1, m2, m3);
}

// ---------------------------------------------------------------------------
// Last round: update + graph pooling with run-length reduction over the
// SORTED batch vector: one atomic per (graph-run, feature) per block
// (~220K atomics total vs 3.2M naive).
// ---------------------------------------------------------------------------
__global__ __launch_bounds__(256) void k_upd_pool(
    const float* __restrict__ updW, const float* __restrict__ updb,
    const float* __restrict__ aggH0, const float* __restrict__ aggH1,
    const float* __restrict__ state, const int* __restrict__ batch,
    float* __restrict__ gs)
{
    __shared__ float sUpdW[STATE * STATE];
    __shared__ float sUpdb[STATE];
    __shared__ float sa[16 * 68];
    __shared__ float ssum[16 * 68];
    __shared__ int   sg[16];

    for (int i = threadIdx.x; i < (STATE * STATE) / 4; i += 256)
        *(float4*)(sUpdW + i * 4) = *(const float4*)(updW + i * 4);
    if (threadIdx.x < STATE) sUpdb[threadIdx.x] = updb[threadIdx.x];

    const int ns = threadIdx.x >> 4;
    const int jg = (threadIdx.x & 15) << 2;
    const int base = blockIdx.x * 16;
    const int n = base + ns;

    {
        int row = threadIdx.x >> 4, q = (threadIdx.x & 15) << 2;
        int nn = base + row;
        float4 v;
        if (q < HALF) v = *(const float4*)(aggH0 + (long)nn * HALF + q);
        else          v = *(const float4*)(aggH1 + (long)nn * HALF + (q - HALF));
        *(float4*)(sa + row * 68 + q) = v;
    }
    if (threadIdx.x < 16) sg[threadIdx.x] = batch[base + threadIdx.x];
    __syncthreads();

    float a0 = sUpdb[jg], a1 = sUpdb[jg + 1], a2 = sUpdb[jg + 2], a3 = sUpdb[jg + 3];
    const float* ar = sa + ns * 68;
    #pragma unroll 8
    for (int k = 0; k < STATE; k++) {
        float av = ar[k];
        float4 w = *(const float4*)(sUpdW + k * STATE + jg);
        a0 += av * w.x; a1 += av * w.y; a2 += av * w.z; a3 += av * w.w;
    }
    a0 = fmaxf(a0, 0.f); a1 = fmaxf(a1, 0.f); a2 = fmaxf(a2, 0.f); a3 = fmaxf(a3, 0.f);
    float4 st = *(const float4*)(state + (long)n * STATE + jg);
    *(float4*)(ssum + ns * 68 + jg) = make_float4(st.x + a0, st.y + a1, st.z + a2, st.w + a3);
    __syncthreads();

    // run-length reduce over the 16 (sorted) nodes; 64 feature-threads
    if (threadIdx.x < STATE) {
        const int f = threadIdx.x;
        float run = ssum[f];
        int g = sg[0];
        #pragma unroll
        for (int r = 1; r < 16; r++) {
            int g2 = sg[r];               // wave-uniform across the 64 threads
            float v = ssum[r * 68 + f];
            if (g2 != g) {
                atomicAdd(&gs[g * STATE + f], run);
                run = v; g = g2;
            } else {
                run += v;
            }
        }
        atomicAdd(&gs[g * STATE + f], run);
    }
}

// ---------------------------------------------------------------------------
// mean = gs@meanW+b ; std = exp(0.5*clip(gs@lvW+b, -20, 2)) -> out[2,256,32]
// ---------------------------------------------------------------------------
__global__ __launch_bounds__(64) void k_final(
    const float* __restrict__ gs,
    const float* __restrict__ meanW, const float* __restrict__ meanb,
    const float* __restrict__ lvW, const float* __restrict__ lvb,
    float* __restrict__ out)
{
    __shared__ float row[STATE];
    const int g = blockIdx.x;
    const int j = threadIdx.x;
    row[j] = gs[g * STATE + j];
    __syncthreads();
    if (j < M_OUT) {
        float acc = meanb[j];
        #pragma unroll
        for (int k = 0; k < STATE; k++) acc += row[k] * meanW[k * M_OUT + j];
        out[g * M_OUT + j] = acc;
    } else {
        int jj = j - M_OUT;
        float acc = lvb[jj];
        #pragma unroll
        for (int k = 0; k < STATE; k++) acc += row[k] * lvW[k * M_OUT + jj];
        acc = fminf(fmaxf(acc, -20.f), 2.f);
        out[GRAPHS * M_OUT + g * M_OUT + jj] = expf(0.5f * acc);
    }
}

extern "C" void kernel_launch(void* const* d_in, const int* in_sizes, int n_in,
                              void* d_out, int out_size, void* d_ws, size_t ws_size,
                              hipStream_t stream) {
    const float* x     = (const float*)d_in[0];
    const int*   ei    = (const int*)d_in[1];   // [2, E]: row0 = src (gather), row1 = dst (scatter)
    const int*   batch = (const int*)d_in[2];
    const float* inW   = (const float*)d_in[3];
    const float* inb   = (const float*)d_in[4];
    const float* msgW  = (const float*)d_in[5]; // [4,64,64]
    const float* msgb  = (const float*)d_in[6]; // [4,64]
    const float* updW  = (const float*)d_in[7];
    const float* updb  = (const float*)d_in[8];
    const float* meanW = (const float*)d_in[9];
    const float* meanb = (const float*)d_in[10];
    const float* lvW   = (const float*)d_in[11];
    const float* lvb   = (const float*)d_in[12];
    float* out = (float*)d_out;

    const size_t NS   = (size_t)NODES * STATE * sizeof(float);  // 12.8 MB state
    const size_t PLB  = (size_t)PLANE * sizeof(bfraw);          //  3.2 MB per bf16 plane
    const size_t AGH  = (size_t)NODES * HALF * sizeof(float);   //  6.4 MB per agg half
    char* ws = (char*)d_ws;
    size_t off = 0;
    auto alloc = [&](size_t bytes) { void* p = ws + off; off += (bytes + 255) & ~(size_t)255; return p; };
    float* state  = (float*)alloc(NS);
    bfraw* msgA0  = (bfraw*)alloc(PLB);
    bfraw* msgA1  = (bfraw*)alloc(PLB);
    bfraw* msgB0  = (bfraw*)alloc(PLB);
    bfraw* msgB1  = (bfraw*)alloc(PLB);
    float* aggH0  = (float*)alloc(AGH);
    float* aggH1  = (float*)alloc(AGH);
    float* gs     = (float*)alloc((size_t)GRAPHS * STATE * sizeof(float));
    int*   deg    = (int*)alloc((size_t)NODES * sizeof(int));
    int*   part   = (int*)alloc((size_t)NODES * sizeof(int));
    int*   bsum   = (int*)alloc((size_t)SCAN_BLOCKS * sizeof(int));
    int*   bcarry = (int*)alloc((size_t)SCAN_BLOCKS * sizeof(int));
    int*   rowptr = (int*)alloc((size_t)(NODES + 1) * sizeof(int));
    int*   cursor = (int*)alloc((size_t)NODES * sizeof(int));
    int*   csr    = (int*)alloc((size_t)EDGES * sizeof(int));

    hipMemsetAsync(deg, 0, (size_t)NODES * sizeof(int), stream);
    hipMemsetAsync(gs, 0, (size_t)GRAPHS * STATE * sizeof(float), stream);

    k_hist<<<(EDGES + 255) / 256, 256, 0, stream>>>(ei, deg);
    k_scan1<<<SCAN_BLOCKS, 1024, 0, stream>>>(deg, part, bsum);
    k_scan2<<<1, 64, 0, stream>>>(bsum, bcarry);
    k_scan3<<<(NODES + 255) / 256, 256, 0, stream>>>(part, bcarry, rowptr, cursor);
    k_fill<<<(EDGES + 255) / 256, 256, 0, stream>>>(ei, cursor, csr);

    k_in_msg<<<NTILES, 256, 0, stream>>>(x, inW, inb, msgW, msgb, state, msgA0, msgA1);

    const int GG = (NODES + 31) / 32; // gather grid: 32 nodes/block, 8 lanes/node
    bfraw *mi0 = msgA0, *mi1 = msgA1, *mo0 = msgB0, *mo1 = msgB1;
    for (int r = 0; r < ROUNDS; r++) {
        k_gather_half<<<GG, 256, 0, stream>>>(rowptr, csr, mi0, aggH0);
        k_gather_half<<<GG, 256, 0, stream>>>(rowptr, csr, mi1, aggH1);
        if (r < ROUNDS - 1) {
            k_upd_msg<<<NTILES, 256, 0, stream>>>(
                updW + r * STATE * STATE, updb + r * STATE,
                msgW + (r + 1) * STATE * STATE, msgb + (r + 1) * STATE,
                aggH0, aggH1, state, mo0, mo1);
            bfraw* t0 = mi0; mi0 = mo0; mo0 = t0;
            bfraw* t1 = mi1; mi1 = mo1; mo1 = t1;
        } else {
            k_upd_pool<<<NTILES, 256, 0, stream>>>(
                updW + r * STATE * STATE, updb + r * STATE,
                aggH0, aggH1, state, batch, gs);
        }
    }

    k_final<<<GRAPHS, 64, 0, stream>>>(gs, meanW, meanb, lvW, lvb, out);
}